// Round 7
// baseline (1817.487 us; speedup 1.0000x reference)
//
#include <hip/hip_runtime.h>
#include <hip/hip_bf16.h>

#define B 64
#define T 256
#define IN 512
#define H 1024
#define L 6

#define NBLK 192            // 6 layers * 32 col tiles
#define TPB 512             // 8 waves
#define NCOL 32             // output cols per block
#define TILES_PER_L 32
#define WROWB 3072          // bytes per W row (1536 bf16), XOR-swizzled, no pad
#define SMEM_W_BYTES (NCOL * WROWB)                // 98304
#define ABUF_BYTES 32768                            // 64 rows x 512 B
#define SMEM_BYTES (SMEM_W_BYTES + 2 * ABUF_BYTES)  // 163840 = 160 KiB

typedef __bf16 bf16x8 __attribute__((ext_vector_type(8)));
typedef __bf16 bf16x4 __attribute__((ext_vector_type(4)));
typedef float f32x4 __attribute__((ext_vector_type(4)));

// ---------------------------------------------------------------------------
// prep: x [B,T,I] fp32 -> xbf [T,B,I] bf16 ; h0 fp32 -> hb0 bf16
// ---------------------------------------------------------------------------
__global__ void prep_kernel(const float* __restrict__ x,
                            const float* __restrict__ h0,
                            __bf16* __restrict__ xbf,
                            __bf16* __restrict__ hb0) {
    const int N4x = B * T * (IN / 4);
    const int N4h = L * B * (H / 4);
    int stride = gridDim.x * blockDim.x;
    for (int u = blockIdx.x * blockDim.x + threadIdx.x; u < N4x + N4h; u += stride) {
        if (u < N4x) {
            int b = u / (T * (IN / 4));
            int r = u % (T * (IN / 4));
            int t = r / (IN / 4), c4 = r % (IN / 4);
            float4 v = reinterpret_cast<const float4*>(x)[u];
            bf16x4 o = {(__bf16)v.x, (__bf16)v.y, (__bf16)v.z, (__bf16)v.w};
            *reinterpret_cast<bf16x4*>(xbf + ((size_t)t * B + b) * IN + c4 * 4) = o;
        } else {
            int j = u - N4x;
            float4 v = reinterpret_cast<const float4*>(h0)[j];
            bf16x4 o = {(__bf16)v.x, (__bf16)v.y, (__bf16)v.z, (__bf16)v.w};
            *reinterpret_cast<bf16x4*>(hb0 + (size_t)j * 4) = o;
        }
    }
}

// ---------------------------------------------------------------------------
// Persistent per-(layer, col-tile) kernel; (l, rank) from blockIdx (no XCD
// games). h + flags exchanged through the Infinity Cache (sc0 sc1 loads and
// stores) -> zero cache-maintenance instructions. Flag-array sync (parallel
// signal + parallel poll). Double-buffered A pipeline: 7 barriers/step.
// ---------------------------------------------------------------------------
__global__ __launch_bounds__(TPB)
void rnn_kernel(const __bf16* __restrict__ xbf,   // [T][B][IN]
                const float*  __restrict__ wih,   // [L][H][IN] fp32
                const float*  __restrict__ whh,   // [L][H][H]  fp32
                const float*  __restrict__ bih,
                const float*  __restrict__ bhh,
                __bf16* __restrict__ hb0,         // [L][B][H]
                __bf16* __restrict__ hb1,
                float*  __restrict__ out,
                unsigned* __restrict__ flags) {   // [L*32]
    extern __shared__ char smem[];
    char* Abase = smem + SMEM_W_BYTES;

    const int l    = blockIdx.x / TILES_PER_L;
    const int rank = blockIdx.x % TILES_PER_L;
    const int n0   = rank * NCOL;
    const int tid  = threadIdx.x;
    const int lane = tid & 63;
    const int wave = tid >> 6;

    // ---- one-time: weight slice fp32 -> bf16 -> LDS (XOR-swizzled units) ---
    for (int u = tid; u < NCOL * 192; u += TPB) {
        int gl = u / 192;              // local output col
        int c  = u % 192;              // 16B unit within the 3072B row
        int k0 = c * 8;
        const float* src = (k0 < IN)
            ? wih + ((size_t)(l * H + n0 + gl)) * IN + k0
            : whh + ((size_t)(l * H + n0 + gl)) * H + (k0 - IN);
        float4 f0 = *reinterpret_cast<const float4*>(src);
        float4 f1 = *reinterpret_cast<const float4*>(src + 4);
        bf16x8 o = {(__bf16)f0.x, (__bf16)f0.y, (__bf16)f0.z, (__bf16)f0.w,
                    (__bf16)f1.x, (__bf16)f1.y, (__bf16)f1.z, (__bf16)f1.w};
        *reinterpret_cast<bf16x8*>(smem + (size_t)gl * WROWB +
                                   ((c ^ (gl & 7)) << 4)) = o;
    }

    const int mw = wave & 3, nw = wave >> 2;
    const int lr = lane & 15, lk = lane >> 4;
    const int g  = n0 + nw * 16 + lr;
    const float bv = bih[l * H + g] + bhh[l * H + g];
    const int arow = mw * 16 + lr, axor = arow & 7;
    const int bgl  = nw * 16 + lr, bxor = bgl & 7;
    const char* Wrow = smem + (size_t)bgl * WROWB;

    const int row0 = tid >> 5, c0 = tid & 31;
    char* wbA = Abase + row0 * 512 + ((c0 ^ (row0 & 7)) << 4);
    char* wbB = wbA + ABUF_BYTES;

#define STAGE_X(SRC, KOFF, WB)                                                  \
    { _Pragma("unroll")                                                         \
      for (int j = 0; j < 4; ++j) {                                             \
          float4 v = *reinterpret_cast<const float4*>(                          \
              (SRC) + (size_t)(row0 + 16 * j) * IN + (KOFF) + c0 * 8);          \
          *reinterpret_cast<float4*>((WB) + j * 8192) = v;                      \
      } }

#define MFMA_CHUNK(BUFOFF, UBASE, ACC0, ACC1)                                   \
    { _Pragma("unroll")                                                         \
      for (int kk = 0; kk < 8; ++kk) {                                          \
          int u = (kk << 2) + lk;                                               \
          bf16x8 af = *reinterpret_cast<const bf16x8*>(                         \
              Abase + (BUFOFF) + arow * 512 + ((u ^ axor) << 4));               \
          bf16x8 bw = *reinterpret_cast<const bf16x8*>(                         \
              Wrow + ((((UBASE) + u) ^ bxor) << 4));                            \
          if (kk & 1) ACC1 = __builtin_amdgcn_mfma_f32_16x16x32_bf16(           \
                                 af, bw, ACC1, 0, 0, 0);                        \
          else        ACC0 = __builtin_amdgcn_mfma_f32_16x16x32_bf16(           \
                                 af, bw, ACC0, 0, 0, 0);                        \
      } }

#define WRITE4(WB, QA, QB, QC, QD)                                              \
    *reinterpret_cast<f32x4*>(WB)           = QA;                               \
    *reinterpret_cast<f32x4*>((WB) + 8192)  = QB;                               \
    *reinterpret_cast<f32x4*>((WB) + 16384) = QC;                               \
    *reinterpret_cast<f32x4*>((WB) + 24576) = QD;

#define VMWAIT(N) do { asm volatile("s_waitcnt vmcnt(" #N ")" ::: "memory");    \
                       __builtin_amdgcn_sched_barrier(0); } while (0)

    const f32x4 zero = {0.f, 0.f, 0.f, 0.f};
    f32x4 hacc0 = zero, hacc1 = zero;     // x-proj(t), then += h-part

    // ---- prologue: x-proj for t=0 (bar1 also flushes the weight fill) ------
    STAGE_X(xbf, 0, wbA);
    __syncthreads();
    STAGE_X(xbf, 256, wbB);
    MFMA_CHUNK(0, 0, hacc0, hacc1);            // x ch0 (bufA, units 0..31)
    __syncthreads();
    MFMA_CHUNK(ABUF_BYTES, 32, hacc0, hacc1);  // x ch1 (bufB, units 32..63)

    for (int t = 0; t < T; ++t) {
        const __bf16* hcur = (t & 1) ? hb1 : hb0;
        __bf16*       hnxt = (t & 1) ? hb0 : hb1;

        // P: wave0 polls all 32 sibling flags in one parallel load (IF-scope)
        if (t > 0 && wave == 0) {
            const unsigned* fa = flags + l * TILES_PER_L + (lane & 31);
            unsigned f;
            for (;;) {
                asm volatile("global_load_dword %0, %1, off sc0 sc1\n\t"
                             "s_waitcnt vmcnt(0)"
                             : "=v"(f) : "v"(fa) : "memory");
                if (__all((int)(f >= (unsigned)t))) break;
                __builtin_amdgcn_s_sleep(1);
            }
        }
        __syncthreads();   // P-bar

        // issue all 16 h loads (IF-coherent); "=&v" early-clobber required
        const char* hsrc = (const char*)(hcur + (size_t)l * B * H);
        const char* ha0 = hsrc + (size_t)(row0 +  0) * 2048 + c0 * 16;
        const char* ha1 = hsrc + (size_t)(row0 + 16) * 2048 + c0 * 16;
        const char* ha2 = hsrc + (size_t)(row0 + 32) * 2048 + c0 * 16;
        const char* ha3 = hsrc + (size_t)(row0 + 48) * 2048 + c0 * 16;
        f32x4 q0,q1,q2,q3,q4,q5,q6,q7,q8,q9,q10,q11,q12,q13,q14,q15;
        asm volatile(
            "global_load_dwordx4 %[q0],  %[a0], off sc0 sc1\n\t"
            "global_load_dwordx4 %[q1],  %[a1], off sc0 sc1\n\t"
            "global_load_dwordx4 %[q2],  %[a2], off sc0 sc1\n\t"
            "global_load_dwordx4 %[q3],  %[a3], off sc0 sc1\n\t"
            "global_load_dwordx4 %[q4],  %[a0], off offset:512 sc0 sc1\n\t"
            "global_load_dwordx4 %[q5],  %[a1], off offset:512 sc0 sc1\n\t"
            "global_load_dwordx4 %[q6],  %[a2], off offset:512 sc0 sc1\n\t"
            "global_load_dwordx4 %[q7],  %[a3], off offset:512 sc0 sc1\n\t"
            "global_load_dwordx4 %[q8],  %[a0], off offset:1024 sc0 sc1\n\t"
            "global_load_dwordx4 %[q9],  %[a1], off offset:1024 sc0 sc1\n\t"
            "global_load_dwordx4 %[q10], %[a2], off offset:1024 sc0 sc1\n\t"
            "global_load_dwordx4 %[q11], %[a3], off offset:1024 sc0 sc1\n\t"
            "global_load_dwordx4 %[q12], %[a0], off offset:1536 sc0 sc1\n\t"
            "global_load_dwordx4 %[q13], %[a1], off offset:1536 sc0 sc1\n\t"
            "global_load_dwordx4 %[q14], %[a2], off offset:1536 sc0 sc1\n\t"
            "global_load_dwordx4 %[q15], %[a3], off offset:1536 sc0 sc1"
            : [q0]"=&v"(q0), [q1]"=&v"(q1), [q2]"=&v"(q2), [q3]"=&v"(q3),
              [q4]"=&v"(q4), [q5]"=&v"(q5), [q6]"=&v"(q6), [q7]"=&v"(q7),
              [q8]"=&v"(q8), [q9]"=&v"(q9), [q10]"=&v"(q10), [q11]"=&v"(q11),
              [q12]"=&v"(q12), [q13]"=&v"(q13), [q14]"=&v"(q14), [q15]"=&v"(q15)
            : [a0]"v"(ha0), [a1]"v"(ha1), [a2]"v"(ha2), [a3]"v"(ha3)
            : "memory");

        // A: write h0 -> bufA                 (vmcnt math is store-count-safe)
        VMWAIT(12); WRITE4(wbA, q0, q1, q2, q3);
        __syncthreads();
        // B: write h1 -> bufB | mfma h0 (bufA, units 64..95)
        VMWAIT(8); WRITE4(wbB, q4, q5, q6, q7);
        MFMA_CHUNK(0, 64, hacc0, hacc1);
        __syncthreads();
        // C: write h2 -> bufA | mfma h1 (bufB)
        VMWAIT(4); WRITE4(wbA, q8, q9, q10, q11);
        MFMA_CHUNK(ABUF_BYTES, 96, hacc0, hacc1);
        __syncthreads();
        // D: write h3 -> bufB | mfma h2 (bufA)
        VMWAIT(0); WRITE4(wbB, q12, q13, q14, q15);
        MFMA_CHUNK(0, 128, hacc0, hacc1);
        __syncthreads();

        const bool more = (t + 1 < T);
        // E: stage x0(t+1) -> bufA | mfma h3 (bufB)
        if (more) { STAGE_X(xbf + (size_t)(t + 1) * B * IN, 0, wbA); }
        MFMA_CHUNK(ABUF_BYTES, 160, hacc0, hacc1);
        __syncthreads();

        // F: stage x1(t+1) -> bufB | mfma x0(t+1) (bufA) | epilogue h-stores
        f32x4 xn0 = zero, xn1 = zero;
        if (more) {
            STAGE_X(xbf + (size_t)(t + 1) * B * IN, 256, wbB);
            MFMA_CHUNK(0, 0, xn0, xn1);
        }
        float vv[4];
        const int brow = mw * 16 + lk * 4;
        {
            #pragma unroll
            for (int j = 0; j < 4; ++j) {
                float v = hacc0[j] + hacc1[j] + bv;
                vv[j] = (v >= 0.f) ? v : 0.01f * v;
            }
            union { __bf16 b; unsigned short u; } cv;
            uint32_t s0, s1, s2, s3;
            cv.b = (__bf16)vv[0]; s0 = cv.u;
            cv.b = (__bf16)vv[1]; s1 = cv.u;
            cv.b = (__bf16)vv[2]; s2 = cv.u;
            cv.b = (__bf16)vv[3]; s3 = cv.u;
            const char* hbp0 = (const char*)(hnxt + ((size_t)(l * B + brow)) * H + g);
            const char* hbp1 = hbp0 + 4096;   // rows +2,+3 (13-bit signed offset)
            asm volatile(
                "global_store_short %[a0], %[v0], off sc0 sc1\n\t"
                "global_store_short %[a0], %[v1], off offset:2048 sc0 sc1\n\t"
                "global_store_short %[a1], %[v2], off sc0 sc1\n\t"
                "global_store_short %[a1], %[v3], off offset:2048 sc0 sc1"
                :: [a0]"v"(hbp0), [a1]"v"(hbp1),
                   [v0]"v"(s0), [v1]"v"(s1), [v2]"v"(s2), [v3]"v"(s3)
                : "memory");
        }
        asm volatile("s_waitcnt vmcnt(0)" ::: "memory");   // h at IF
        __syncthreads();   // F-bar: whole block's h_t+1 visible

        if (tid == 0) {    // signal: one IF-coherent flag store (no RMW)
            unsigned val = (unsigned)(t + 1);
            unsigned* fp = flags + l * TILES_PER_L + rank;
            asm volatile("global_store_dword %0, %1, off sc0 sc1"
                         :: "v"(fp), "v"(val) : "memory");
        }

        // out-stores AFTER the signal (not part of the inter-block protocol)
        #pragma unroll
        for (int j = 0; j < 4; ++j) {
            int b = brow + j;
            if (l == L - 1) out[((size_t)b * T + t) * H + g] = vv[j];
            if (t == T - 1)
                out[(size_t)B * T * H + ((size_t)(l * B + b)) * H + g] = vv[j];
        }

        // G: mfma x1(t+1) (bufB); roll accumulators
        if (more) { MFMA_CHUNK(ABUF_BYTES, 32, xn0, xn1); }
        hacc0 = xn0; hacc1 = xn1;
    }
}

// ---------------------------------------------------------------------------
extern "C" void kernel_launch(void* const* d_in, const int* in_sizes, int n_in,
                              void* d_out, int out_size, void* d_ws, size_t ws_size,
                              hipStream_t stream) {
    const float* x   = (const float*)d_in[0];
    const float* h0  = (const float*)d_in[1];
    const float* wih = (const float*)d_in[2];
    const float* whh = (const float*)d_in[3];
    const float* bih = (const float*)d_in[4];
    const float* bhh = (const float*)d_in[5];
    float* out = (float*)d_out;

    char* ws = (char*)d_ws;
    __bf16* xbf = (__bf16*)ws;                                   // 16 MB
    __bf16* hb0 = (__bf16*)(ws + (size_t)16777216);              // 768 KB
    __bf16* hb1 = (__bf16*)(ws + (size_t)16777216 + 786432);     // 768 KB
    unsigned* flags = (unsigned*)(ws + (size_t)16777216 + 2 * 786432); // 768 B

    hipMemsetAsync(flags, 0, L * TILES_PER_L * sizeof(unsigned), stream);
    prep_kernel<<<2048, 256, 0, stream>>>(x, h0, xbf, hb0);

    static bool attr_done = []() {
        hipFuncSetAttribute((const void*)rnn_kernel,
                            hipFuncAttributeMaxDynamicSharedMemorySize,
                            SMEM_BYTES);
        return true;
    }();
    (void)attr_done;

    rnn_kernel<<<NBLK, TPB, SMEM_BYTES, stream>>>(
        xbf, wih, whh, bih, bhh, hb0, hb1, out, flags);
}